// Round 3
// baseline (485.805 us; speedup 1.0000x reference)
//
#include <hip/hip_runtime.h>
#include <stdint.h>

#define C96   96
#define TOTEL 25165824L   // 8*128*256*96

typedef __attribute__((ext_vector_type(16))) float f32x16;
typedef __attribute__((ext_vector_type(8)))  short short8;

// ---- LDS layout (bytes). Row stride for [*][96] bf16 tiles = 104 elems = 208 B
//      (208%16==0 b128-aligned). Per-row pad bytes 192..207 hold {mu,rs} f32.
#define KQ_OFF 0         // K-side Q bf16 [256] rows x 208 B = 53248
#define SC_OFF 53248     // staging [128] rows x 208 B = 26624  (phase 1)
#define XT_OFF 53248     // raw X tile [64] rows x 208 B = 13312 (phase 2)
#define VT_OFF 66560     // V^T bf16 [96] rows x 144 B = 13824
#define LDS_SZ 80384     // 2 blocks/CU (160768 <= 163840)

#define MFMA32(a,b,c) __builtin_amdgcn_mfma_f32_32x32x16_bf16(a,b,c,0,0,0)

__device__ __forceinline__ uint32_t cvtpk(float lo, float hi) {
    uint32_t d;
    asm("v_cvt_pk_bf16_f32 %0, %1, %2" : "=v"(d) : "v"(lo), "v"(hi));
    return d;
}
__device__ __forceinline__ float bl(uint32_t u){ union{uint32_t i;float f;}a; a.i=u<<16;        return a.f; }
__device__ __forceinline__ float bh(uint32_t u){ union{uint32_t i;float f;}a; a.i=u&0xffff0000u; return a.f; }

union F8 { uint32_t u[4]; short8 s; uint4 q; };

// coalesced global f32 -> LDS bf16 rows (stride 208 B)
template<int ITERS>
__device__ __forceinline__ void stage(const float* __restrict__ src, char* dst, int t) {
#pragma unroll
    for (int i = 0; i < ITERS; ++i) {
        const int idx4 = i * 512 + t;
        const float4 v = *(const float4*)(src + (size_t)idx4 * 4);
        const int r = idx4 / 24;
        const int c = (idx4 % 24) * 4;
        uint2 p; p.x = cvtpk(v.x, v.y); p.y = cvtpk(v.z, v.w);
        *(uint2*)(dst + r * 208 + c * 2) = p;
    }
}

// LN stats for the 128-row SC chunk; stored in each row's pad bytes (+192)
__device__ __forceinline__ void stats128(char* lds, int t) {
    if (t < 128) {
        const char* row = lds + SC_OFF + t * 208;
        float sm = 0.f, s2 = 0.f;
#pragma unroll
        for (int i = 0; i < 12; ++i) {
            F8 w; w.q = *(const uint4*)(row + i * 16);
#pragma unroll
            for (int j = 0; j < 4; ++j) {
                const float a = bl(w.u[j]), b = bh(w.u[j]);
                sm += a + b; s2 += a * a + b * b;
            }
        }
        const float mu = sm * (1.f / 96.f);
        float var = s2 * (1.f / 96.f) - mu * mu;
        var = fmaxf(var, 0.f);
        *(float2*)(lds + SC_OFF + t * 208 + 192) = make_float2(mu, rsqrtf(var + 1e-6f));
    }
}

// Q^T fragments = W1 * LN(X)^T for 32 rows (local row = rloc..rloc+31 at lane l31).
// Output qa[mf][reg]: C-layout col n = local row (l31), row d = mf*32+8*(reg>>2)+4*s+(reg&3).
__device__ __forceinline__ void proj96(const char* lds_, int rloc,
    const float* __restrict__ W1, const float* __restrict__ gv,
    const float* __restrict__ bv, int l31, int s, f32x16* qa)
{
    const char* row = lds_ + SC_OFF + (rloc + l31) * 208;
    const float2 st = *(const float2*)(row + 192);
    const float mu = st.x, rs = st.y;
    short8 bf[6];
#pragma unroll
    for (int kf = 0; kf < 6; ++kf) {
        const int c0 = kf * 16 + s * 8;
        F8 raw; raw.q = *(const uint4*)(row + c0 * 2);
        const float4 g0 = *(const float4*)(gv + c0);
        const float4 g1 = *(const float4*)(gv + c0 + 4);
        const float4 b0 = *(const float4*)(bv + c0);
        const float4 b1 = *(const float4*)(bv + c0 + 4);
        const float x0=bl(raw.u[0]),x1=bh(raw.u[0]),x2=bl(raw.u[1]),x3=bh(raw.u[1]);
        const float x4=bl(raw.u[2]),x5=bh(raw.u[2]),x6=bl(raw.u[3]),x7=bh(raw.u[3]);
        F8 o;
        o.u[0] = cvtpk((x0-mu)*rs*g0.x + b0.x, (x1-mu)*rs*g0.y + b0.y);
        o.u[1] = cvtpk((x2-mu)*rs*g0.z + b0.z, (x3-mu)*rs*g0.w + b0.w);
        o.u[2] = cvtpk((x4-mu)*rs*g1.x + b1.x, (x5-mu)*rs*g1.y + b1.y);
        o.u[3] = cvtpk((x6-mu)*rs*g1.z + b1.z, (x7-mu)*rs*g1.w + b1.w);
        bf[kf] = o.s;
    }
#pragma unroll
    for (int i = 0; i < 16; ++i) { qa[0][i] = 0.f; qa[1][i] = 0.f; qa[2][i] = 0.f; }
#pragma unroll
    for (int kf = 0; kf < 6; ++kf) {
#pragma unroll
        for (int mf = 0; mf < 3; ++mf) {
            const float* wp = W1 + (mf * 32 + l31) * 96 + kf * 16 + s * 8;
            const float4 a0 = *(const float4*)wp;
            const float4 a1 = *(const float4*)(wp + 4);
            F8 af;
            af.u[0] = cvtpk(a0.x, a0.y); af.u[1] = cvtpk(a0.z, a0.w);
            af.u[2] = cvtpk(a1.x, a1.y); af.u[3] = cvtpk(a1.z, a1.w);
            qa[mf] = MFMA32(af.s, bf[kf], qa[mf]);
        }
    }
}

extern "C" __global__ __launch_bounds__(512, 4) void scam_dir(
    const float* __restrict__ feat_l, const float* __restrict__ feat_r,
    const float* __restrict__ g_nl, const float* __restrict__ b_nl,
    const float* __restrict__ g_nr, const float* __restrict__ b_nr,
    const float* __restrict__ w_l1, const float* __restrict__ bias_l1,
    const float* __restrict__ w_r1, const float* __restrict__ bias_r1,
    const float* __restrict__ w_l2, const float* __restrict__ bias_l2,
    const float* __restrict__ w_r2, const float* __restrict__ bias_r2,
    const float* __restrict__ beta, const float* __restrict__ gamma,
    float* __restrict__ out)
{
    extern __shared__ char lds[];
    const int t    = threadIdx.x;
    const int wv   = t >> 6;
    const int lane = t & 63;
    const int l31  = lane & 31;
    const int s    = lane >> 5;
    const int slice = blockIdx.x >> 1;
    const int dir   = blockIdx.x & 1;
    const size_t eb = (size_t)slice * (256 * C96);

    const float* Xq  = dir ? feat_r  : feat_l;   // q-side (also residual)
    const float* Xk  = dir ? feat_l  : feat_r;   // K-side (also V source)
    const float* gq  = dir ? g_nr    : g_nl;
    const float* bqn = dir ? b_nr    : b_nl;
    const float* gk  = dir ? g_nl    : g_nr;
    const float* bkn = dir ? b_nl    : b_nr;
    const float* W1q = dir ? w_r1    : w_l1;
    const float* B1q = dir ? bias_r1 : bias_l1;
    const float* W1k = dir ? w_l1    : w_r1;
    const float* B1k = dir ? bias_l1 : bias_r1;
    const float* W2  = dir ? w_l2    : w_r2;
    const float* B2  = dir ? bias_l2 : bias_r2;
    const float* mixv = dir ? gamma  : beta;
    float* o = out + (dir ? TOTEL : 0) + eb;

    short8 bq[6];           // q-side B-fragments, persistent
    const float scale = 0.10206207261596577f;   // 96^-0.5, folded into q-side

    // ================= phase 1a: q-side Q -> registers =================
#pragma unroll
    for (int ch = 0; ch < 2; ++ch) {
        stage<6>(Xq + eb + (size_t)ch * 128 * 96, lds + SC_OFF, t);
        __syncthreads();
        stats128(lds, t);
        __syncthreads();
        if ((wv >> 2) == ch) {
            f32x16 qa[3];
            proj96(lds, (wv & 3) * 32, W1q, gq, bqn, l31, s, qa);
            // permute C-layout -> B-fragment layout (k = s*8 + j)
#pragma unroll
            for (int mf = 0; mf < 3; ++mf) {
                uint32_t w[4][2], x[4][2];
#pragma unroll
                for (int blk = 0; blk < 4; ++blk) {
                    const int d = mf * 32 + blk * 8 + s * 4;
                    const float4 bb = *(const float4*)(B1q + d);
                    w[blk][0] = cvtpk((qa[mf][blk*4+0] + bb.x) * scale,
                                      (qa[mf][blk*4+1] + bb.y) * scale);
                    w[blk][1] = cvtpk((qa[mf][blk*4+2] + bb.z) * scale,
                                      (qa[mf][blk*4+3] + bb.w) * scale);
                    x[blk][0] = __shfl_xor(w[blk][0], 32);
                    x[blk][1] = __shfl_xor(w[blk][1], 32);
                }
#pragma unroll
                for (int p = 0; p < 2; ++p) {
                    F8 oo;
                    oo.u[0] = s ? x[2*p+1][0] : w[2*p][0];
                    oo.u[1] = s ? x[2*p+1][1] : w[2*p][1];
                    oo.u[2] = s ? w[2*p+1][0] : x[2*p][0];
                    oo.u[3] = s ? w[2*p+1][1] : x[2*p][1];
                    bq[mf*2+p] = oo.s;
                }
            }
        }
        __syncthreads();
    }
    // ================= phase 1b: K-side Q -> LDS =================
#pragma unroll
    for (int ch = 0; ch < 2; ++ch) {
        stage<6>(Xk + eb + (size_t)ch * 128 * 96, lds + SC_OFF, t);
        __syncthreads();
        stats128(lds, t);
        __syncthreads();
        if ((wv >> 2) == ch) {
            f32x16 qa[3];
            proj96(lds, (wv & 3) * 32, W1k, gk, bkn, l31, s, qa);
            const int r = ch * 128 + (wv & 3) * 32 + l31;
#pragma unroll
            for (int mf = 0; mf < 3; ++mf) {
#pragma unroll
                for (int blk = 0; blk < 4; ++blk) {
                    const int d = mf * 32 + blk * 8 + s * 4;
                    const float4 bb = *(const float4*)(B1k + d);
                    uint2 p;
                    p.x = cvtpk(qa[mf][blk*4+0] + bb.x, qa[mf][blk*4+1] + bb.y);
                    p.y = cvtpk(qa[mf][blk*4+2] + bb.z, qa[mf][blk*4+3] + bb.w);
                    *(uint2*)(lds + KQ_OFF + r * 208 + d * 2) = p;
                }
            }
        }
        __syncthreads();
    }

    // ================= phase 2: flash attention, one direction =================
    f32x16 O[3];
#pragma unroll
    for (int i = 0; i < 16; ++i) { O[0][i] = 0.f; O[1][i] = 0.f; O[2][i] = 0.f; }
    float m_run = -1e30f, l_run = 0.f;
    const int mfv = wv % 3, nfv = wv / 3;

    stage<3>(Xk + eb, lds + XT_OFF, t);     // prologue: V-source tile 0

    for (int vt = 0; vt < 4; ++vt) {
        __syncthreads();                    // XT(vt) ready (and KQ complete)
        if (wv < 6) {
            f32x16 va;
#pragma unroll
            for (int i = 0; i < 16; ++i) va[i] = 0.f;
#pragma unroll
            for (int kf = 0; kf < 6; ++kf) {
                const float* wp = W2 + (mfv * 32 + l31) * 96 + kf * 16 + s * 8;
                const float4 a0 = *(const float4*)wp;
                const float4 a1 = *(const float4*)(wp + 4);
                F8 af;
                af.u[0] = cvtpk(a0.x, a0.y); af.u[1] = cvtpk(a0.z, a0.w);
                af.u[2] = cvtpk(a1.x, a1.y); af.u[3] = cvtpk(a1.z, a1.w);
                const short8 xb = *(const short8*)(lds + XT_OFF + (nfv * 32 + l31) * 208 + kf * 32 + s * 16);
                va = MFMA32(af.s, xb, va);
            }
            const int v = nfv * 32 + l31;
#pragma unroll
            for (int blk = 0; blk < 4; ++blk) {
                const int d = mfv * 32 + blk * 8 + s * 4;
                const float4 bb = *(const float4*)(B2 + d);
                *(uint16_t*)(lds + VT_OFF + (d+0) * 144 + v * 2) = (uint16_t)cvtpk(va[blk*4+0] + bb.x, 0.f);
                *(uint16_t*)(lds + VT_OFF + (d+1) * 144 + v * 2) = (uint16_t)cvtpk(va[blk*4+1] + bb.y, 0.f);
                *(uint16_t*)(lds + VT_OFF + (d+2) * 144 + v * 2) = (uint16_t)cvtpk(va[blk*4+2] + bb.z, 0.f);
                *(uint16_t*)(lds + VT_OFF + (d+3) * 144 + v * 2) = (uint16_t)cvtpk(va[blk*4+3] + bb.w, 0.f);
            }
        }
        __syncthreads();                    // VT ready; XT dead
        if (vt < 3) stage<3>(Xk + eb + (size_t)(vt + 1) * 64 * 96, lds + XT_OFF, t);

#pragma unroll
        for (int half = 0; half < 2; ++half) {
            f32x16 sa;
#pragma unroll
            for (int i = 0; i < 16; ++i) sa[i] = 0.f;
#pragma unroll
            for (int kf = 0; kf < 6; ++kf) {
                const short8 a0 = *(const short8*)(lds + KQ_OFF + (vt * 64 + half * 32 + l31) * 208 + kf * 32 + s * 16);
                sa = MFMA32(a0, bq[kf], sa);
            }
            // online softmax over these 32 v (split across the two s-halves)
            float tm = -1e30f;
#pragma unroll
            for (int i = 0; i < 16; ++i) tm = fmaxf(tm, sa[i]);
            tm = fmaxf(tm, __shfl_xor(tm, 32));
            const float mn = fmaxf(m_run, tm);
            const float al = __expf(m_run - mn);
            float ps = 0.f;
#pragma unroll
            for (int i = 0; i < 16; ++i) { sa[i] = __expf(sa[i] - mn); ps += sa[i]; }
            ps += __shfl_xor(ps, 32);
            l_run = l_run * al + ps;
            m_run = mn;
            O[0] *= al; O[1] *= al; O[2] *= al;
            // PV: O^T += V^T * P^T, P fragments built in-register
#pragma unroll
            for (int kc = 0; kc < 2; ++kc) {
                const int base = kc * 8;
                const uint32_t A0 = cvtpk(sa[base+0], sa[base+1]);
                const uint32_t A1 = cvtpk(sa[base+2], sa[base+3]);
                const uint32_t B0 = cvtpk(sa[base+4], sa[base+5]);
                const uint32_t B1 = cvtpk(sa[base+6], sa[base+7]);
                const uint32_t rA0 = __shfl_xor(A0, 32);
                const uint32_t rA1 = __shfl_xor(A1, 32);
                const uint32_t rB0 = __shfl_xor(B0, 32);
                const uint32_t rB1 = __shfl_xor(B1, 32);
                F8 pb;
                pb.u[0] = s ? rB0 : A0;
                pb.u[1] = s ? rB1 : A1;
                pb.u[2] = s ? B0  : rA0;
                pb.u[3] = s ? B1  : rA1;
#pragma unroll
                for (int mf2 = 0; mf2 < 3; ++mf2) {
                    const short8 av = *(const short8*)(lds + VT_OFF + (mf2 * 32 + l31) * 144 + half * 64 + kc * 32 + s * 16);
                    O[mf2] = MFMA32(av, pb.s, O[mf2]);
                }
            }
        }
    }

    // ---- epilogue: out = x_res + (O/l) * mix ----
    const float inv = 1.f / l_run;
    const size_t rowbase = eb + (size_t)(wv * 32 + l31) * 96;
#pragma unroll
    for (int mf = 0; mf < 3; ++mf) {
#pragma unroll
        for (int blk = 0; blk < 4; ++blk) {
            const int d = mf * 32 + blk * 8 + s * 4;
            const float4 mx = *(const float4*)(mixv + d);
            const float4 xr = *(const float4*)(Xq + rowbase + d);
            float4 ov;
            ov.x = fmaf(O[mf][blk*4+0] * inv, mx.x, xr.x);
            ov.y = fmaf(O[mf][blk*4+1] * inv, mx.y, xr.y);
            ov.z = fmaf(O[mf][blk*4+2] * inv, mx.z, xr.z);
            ov.w = fmaf(O[mf][blk*4+3] * inv, mx.w, xr.w);
            *(float4*)(out + (dir ? TOTEL : 0) + rowbase + d) = ov;
        }
    }
}

extern "C" void kernel_launch(void* const* d_in, const int* in_sizes, int n_in,
                              void* d_out, int out_size, void* d_ws, size_t ws_size,
                              hipStream_t stream) {
    const float* feat_l  = (const float*)d_in[0];
    const float* feat_r  = (const float*)d_in[1];
    const float* g_nl    = (const float*)d_in[2];
    const float* b_nl    = (const float*)d_in[3];
    const float* g_nr    = (const float*)d_in[4];
    const float* b_nr    = (const float*)d_in[5];
    const float* w_l1    = (const float*)d_in[6];
    const float* bias_l1 = (const float*)d_in[7];
    const float* w_r1    = (const float*)d_in[8];
    const float* bias_r1 = (const float*)d_in[9];
    const float* w_l2    = (const float*)d_in[10];
    const float* bias_l2 = (const float*)d_in[11];
    const float* w_r2    = (const float*)d_in[12];
    const float* bias_r2 = (const float*)d_in[13];
    const float* beta    = (const float*)d_in[14];
    const float* gamma   = (const float*)d_in[15];
    float* out = (float*)d_out;

    hipLaunchKernelGGL(scam_dir, dim3(2048), dim3(512), LDS_SZ, stream,
                       feat_l, feat_r, g_nl, b_nl, g_nr, b_nr,
                       w_l1, bias_l1, w_r1, bias_r1, w_l2, bias_l2, w_r2, bias_r2,
                       beta, gamma, out);
}

// Round 4
// 215.229 us; speedup vs baseline: 2.2572x; 2.2572x over previous
//
#include <hip/hip_runtime.h>
#include <stdint.h>

#define C96   96
#define TOTEL 25165824L   // 8*128*256*96

typedef __attribute__((ext_vector_type(16))) float f32x16;
typedef __attribute__((ext_vector_type(8)))  short short8;

// ---- LDS layout (bytes). Tile rows stride 208 B (104 bf16): b128-aligned,
//      52-word period -> 4-way max on b128 reads. Row pad [192..207] = {mu,rs}.
#define QL_OFF  0         // Q_l (raw X_l during stage) [256][208] = 53248
#define QR_OFF  53248     // Q_r (raw X_r during stage) [256][208] = 53248
#define XT0_OFF 106496    // V-source raw tile, buf0 [64][208] = 13312
#define XT1_OFF 119808    // buf1
#define VT0_OFF 133120    // V^T bf16 [96][144B] = 13824, buf0
#define VT1_OFF 146944    // buf1 -> end 160768
// phase-1 overlay (temporally disjoint with XT/VT):
#define W1Q_OFF 106496    // W1 q-side bf16 [96][208] = 19968
#define W1K_OFF 126464    // W1 K-side bf16 [96][208] = 19968 -> end 146432
#define LDS_SZ  160768

#define MFMA32(a,b,c) __builtin_amdgcn_mfma_f32_32x32x16_bf16(a,b,c,0,0,0)

__device__ __forceinline__ uint32_t cvtpk(float lo, float hi) {
    uint32_t d;
    asm("v_cvt_pk_bf16_f32 %0, %1, %2" : "=v"(d) : "v"(lo), "v"(hi));
    return d;
}
__device__ __forceinline__ float bl(uint32_t u){ union{uint32_t i;float f;}a; a.i=u<<16;        return a.f; }
__device__ __forceinline__ float bh(uint32_t u){ union{uint32_t i;float f;}a; a.i=u&0xffff0000u; return a.f; }

union F8 { uint32_t u[4]; short8 s; uint4 q; };

// coalesced global f32 -> LDS bf16 rows (stride 208 B)
template<int ITERS>
__device__ __forceinline__ void stage(const float* __restrict__ src, char* dst, int t) {
#pragma unroll
    for (int i = 0; i < ITERS; ++i) {
        const int idx4 = i * 512 + t;
        const float4 v = *(const float4*)(src + (size_t)idx4 * 4);
        const int r = idx4 / 24;
        const int c = (idx4 % 24) * 4;
        uint2 p; p.x = cvtpk(v.x, v.y); p.y = cvtpk(v.z, v.w);
        *(uint2*)(dst + r * 208 + c * 2) = p;
    }
}

// W matrix (96x96 f32 global) -> LDS bf16 stride 208
__device__ __forceinline__ void stageW(const float* __restrict__ W, char* dst, int t) {
#pragma unroll
    for (int i = 0; i < 5; ++i) {
        const int idx4 = i * 512 + t;
        if (idx4 < 2304) {
            const float4 v = *(const float4*)(W + (size_t)idx4 * 4);
            const int r = idx4 / 24;
            const int c = (idx4 % 24) * 4;
            uint2 p; p.x = cvtpk(v.x, v.y); p.y = cvtpk(v.z, v.w);
            *(uint2*)(dst + r * 208 + c * 2) = p;
        }
    }
}

// LN stats for all 512 rows (t<256: QL rows, t>=256: QR rows) -> row pads
__device__ __forceinline__ void stats512(char* lds_, int t) {
    char* row = lds_ + ((t < 256) ? QL_OFF : QR_OFF) + (t & 255) * 208;
    float sm = 0.f, s2 = 0.f;
#pragma unroll
    for (int i = 0; i < 12; ++i) {
        F8 w; w.q = *(const uint4*)(row + i * 16);
#pragma unroll
        for (int j = 0; j < 4; ++j) {
            const float a = bl(w.u[j]), b = bh(w.u[j]);
            sm += a + b; s2 += a * a + b * b;
        }
    }
    const float mu = sm * (1.f / 96.f);
    float var = s2 * (1.f / 96.f) - mu * mu;
    var = fmaxf(var, 0.f);
    *(float2*)(row + 192) = make_float2(mu, rsqrtf(var + 1e-6f));
}

// In-place LN + Q-projection for this wave's 32 rows. W from LDS bf16.
// Safe in-place: each lane reads only row (wv*32+l31), all reads (bf[]) complete
// before the MFMA chain finishes, writes go to the same row after.
__device__ __forceinline__ void proj_inplace(char* lds_, int qoff, int woff,
    const float* __restrict__ gv, const float* __restrict__ bv,
    const float* __restrict__ bias1, float outscale, int wv, int l31, int s)
{
    char* row = lds_ + qoff + (wv * 32 + l31) * 208;
    const float2 st = *(const float2*)(row + 192);
    const float mu = st.x, rs = st.y;
    short8 bf[6];
#pragma unroll
    for (int kf = 0; kf < 6; ++kf) {
        const int c0 = kf * 16 + s * 8;
        F8 raw; raw.q = *(const uint4*)(row + c0 * 2);
        const float4 g0 = *(const float4*)(gv + c0);
        const float4 g1 = *(const float4*)(gv + c0 + 4);
        const float4 b0 = *(const float4*)(bv + c0);
        const float4 b1 = *(const float4*)(bv + c0 + 4);
        const float x0=bl(raw.u[0]),x1=bh(raw.u[0]),x2=bl(raw.u[1]),x3=bh(raw.u[1]);
        const float x4=bl(raw.u[2]),x5=bh(raw.u[2]),x6=bl(raw.u[3]),x7=bh(raw.u[3]);
        F8 o;
        o.u[0] = cvtpk((x0-mu)*rs*g0.x + b0.x, (x1-mu)*rs*g0.y + b0.y);
        o.u[1] = cvtpk((x2-mu)*rs*g0.z + b0.z, (x3-mu)*rs*g0.w + b0.w);
        o.u[2] = cvtpk((x4-mu)*rs*g1.x + b1.x, (x5-mu)*rs*g1.y + b1.y);
        o.u[3] = cvtpk((x6-mu)*rs*g1.z + b1.z, (x7-mu)*rs*g1.w + b1.w);
        bf[kf] = o.s;
    }
    f32x16 qa[3];
#pragma unroll
    for (int i = 0; i < 16; ++i) { qa[0][i] = 0.f; qa[1][i] = 0.f; qa[2][i] = 0.f; }
#pragma unroll
    for (int kf = 0; kf < 6; ++kf) {
#pragma unroll
        for (int mf = 0; mf < 3; ++mf) {
            const short8 af = *(const short8*)(lds_ + woff + (mf * 32 + l31) * 208 + kf * 32 + s * 16);
            qa[mf] = MFMA32(af, bf[kf], qa[mf]);
        }
    }
#pragma unroll
    for (int mf = 0; mf < 3; ++mf) {
#pragma unroll
        for (int blk = 0; blk < 4; ++blk) {
            const int d = mf * 32 + blk * 8 + s * 4;
            const float4 bb = *(const float4*)(bias1 + d);
            uint2 p;
            p.x = cvtpk((qa[mf][blk*4+0] + bb.x) * outscale, (qa[mf][blk*4+1] + bb.y) * outscale);
            p.y = cvtpk((qa[mf][blk*4+2] + bb.z) * outscale, (qa[mf][blk*4+3] + bb.w) * outscale);
            *(uint2*)(row + d * 2) = p;
        }
    }
}

// V projection for one 64-row tile: V^T[d][v] from raw XT buffer
__device__ __forceinline__ void vproj(char* lds_, int xt_off, int vt_off,
    const short8* wf, const float* __restrict__ B2, int mfv, int nfv, int l31, int s)
{
    f32x16 va;
#pragma unroll
    for (int i = 0; i < 16; ++i) va[i] = 0.f;
#pragma unroll
    for (int kf = 0; kf < 6; ++kf) {
        const short8 xb = *(const short8*)(lds_ + xt_off + (nfv * 32 + l31) * 208 + kf * 32 + s * 16);
        va = MFMA32(wf[kf], xb, va);
    }
    const int v = nfv * 32 + l31;
#pragma unroll
    for (int blk = 0; blk < 4; ++blk) {
        const int d = mfv * 32 + blk * 8 + s * 4;
        const float4 bb = *(const float4*)(B2 + d);
        *(uint16_t*)(lds_ + vt_off + (d+0) * 144 + v * 2) = (uint16_t)cvtpk(va[blk*4+0] + bb.x, 0.f);
        *(uint16_t*)(lds_ + vt_off + (d+1) * 144 + v * 2) = (uint16_t)cvtpk(va[blk*4+1] + bb.y, 0.f);
        *(uint16_t*)(lds_ + vt_off + (d+2) * 144 + v * 2) = (uint16_t)cvtpk(va[blk*4+2] + bb.z, 0.f);
        *(uint16_t*)(lds_ + vt_off + (d+3) * 144 + v * 2) = (uint16_t)cvtpk(va[blk*4+3] + bb.w, 0.f);
    }
}

// S^T tile (both 32-row halves) from K-region + cached bq
__device__ __forceinline__ void scalc(const char* lds_, int koff, int vt,
                                      const short8* bq, int l31, int s, f32x16* sa)
{
#pragma unroll
    for (int i = 0; i < 16; ++i) { sa[0][i] = 0.f; sa[1][i] = 0.f; }
#pragma unroll
    for (int kf = 0; kf < 6; ++kf) {
        const short8 a0 = *(const short8*)(lds_ + koff + (vt * 64 +      l31) * 208 + kf * 32 + s * 16);
        const short8 a1 = *(const short8*)(lds_ + koff + (vt * 64 + 32 + l31) * 208 + kf * 32 + s * 16);
        sa[0] = MFMA32(a0, bq[kf], sa[0]);
        sa[1] = MFMA32(a1, bq[kf], sa[1]);
    }
}

extern "C" __global__ __launch_bounds__(512, 2) void scam_fused(
    const float* __restrict__ feat_l, const float* __restrict__ feat_r,
    const float* __restrict__ g_nl, const float* __restrict__ b_nl,
    const float* __restrict__ g_nr, const float* __restrict__ b_nr,
    const float* __restrict__ w_l1, const float* __restrict__ bias_l1,
    const float* __restrict__ w_r1, const float* __restrict__ bias_r1,
    const float* __restrict__ w_l2, const float* __restrict__ bias_l2,
    const float* __restrict__ w_r2, const float* __restrict__ bias_r2,
    const float* __restrict__ beta, const float* __restrict__ gamma,
    float* __restrict__ out)
{
    extern __shared__ char lds[];
    const int t    = threadIdx.x;
    const int wv   = t >> 6;
    const int lane = t & 63;
    const int l31  = lane & 31;
    const int s    = lane >> 5;
    const size_t eb = (size_t)blockIdx.x * (256 * C96);
    const float scale = 0.10206207261596577f;   // 96^-0.5, folded into stored Q_l

    // ================= phase 1: both Q projections, minimal barriers =================
    stage<12>(feat_l + eb, lds + QL_OFF, t);
    stage<12>(feat_r + eb, lds + QR_OFF, t);
    stageW(w_l1, lds + (0 ? W1K_OFF : W1Q_OFF), t);   // W for Q_l
    stageW(w_r1, lds + W1K_OFF, t);                   // W for Q_r
    __syncthreads();
    stats512(lds, t);
    __syncthreads();
    proj_inplace(lds, QL_OFF, W1Q_OFF, g_nl, b_nl, bias_l1, scale, wv, l31, s);
    proj_inplace(lds, QR_OFF, W1K_OFF, g_nr, b_nr, bias_r1, 1.0f,  wv, l31, s);

    // ================= phase 2: dual-direction flash attention =================
    for (int dir = 0; dir < 2; ++dir) {
        const int qoff = dir ? QR_OFF : QL_OFF;      // q-side (B-frags)
        const int koff = dir ? QL_OFF : QR_OFF;      // K-side (A-frags)
        const float* Xk   = dir ? feat_l  : feat_r;  // V source
        const float* Xq   = dir ? feat_r  : feat_l;  // residual
        const float* W2   = dir ? w_l2    : w_r2;
        const float* B2   = dir ? bias_l2 : bias_r2;
        const float* mixv = dir ? gamma   : beta;

        short8 bq[6];
#pragma unroll
        for (int kf = 0; kf < 6; ++kf)
            bq[kf] = *(const short8*)(lds + qoff + (wv * 32 + l31) * 208 + kf * 32 + s * 16);

        short8 wf[6];
        const int mfv = wv % 3, nfv = wv / 3;
        if (wv < 6) {
#pragma unroll
            for (int kf = 0; kf < 6; ++kf) {
                const float* wp = W2 + (mfv * 32 + l31) * 96 + kf * 16 + s * 8;
                const float4 a0 = *(const float4*)wp;
                const float4 a1 = *(const float4*)(wp + 4);
                F8 af;
                af.u[0] = cvtpk(a0.x, a0.y); af.u[1] = cvtpk(a0.z, a0.w);
                af.u[2] = cvtpk(a1.x, a1.y); af.u[3] = cvtpk(a1.z, a1.w);
                wf[kf] = af.s;
            }
        }

        f32x16 O[3];
#pragma unroll
        for (int i = 0; i < 16; ++i) { O[0][i] = 0.f; O[1][i] = 0.f; O[2][i] = 0.f; }
        float m_run = -1e30f, l_run = 0.f;
        f32x16 sab[2][2];

        __syncthreads();                 // boundary: phase1 W-reads / prev-dir VT reads done
        stage<3>(Xk + eb, lds + XT0_OFF, t);
        __syncthreads();                 // XT0 ready
        if (wv < 6) vproj(lds, XT0_OFF, VT0_OFF, wf, B2, mfv, nfv, l31, s);
        stage<3>(Xk + eb + 64 * 96, lds + XT1_OFF, t);
        __syncthreads();                 // VT0 + XT1 ready
        scalc(lds, koff, 0, bq, l31, s, sab[0]);

#pragma unroll
        for (int vt = 0; vt < 4; ++vt) {
            const int cb = vt & 1, nb = cb ^ 1;
            if (vt < 3) scalc(lds, koff, vt + 1, bq, l31, s, sab[nb]);  // overlaps softmax below

            // ---- online softmax over this tile's 64 v ----
            f32x16* sa = sab[cb];
            float tm = -1e30f;
#pragma unroll
            for (int i = 0; i < 16; ++i) { tm = fmaxf(tm, sa[0][i]); tm = fmaxf(tm, sa[1][i]); }
            tm = fmaxf(tm, __shfl_xor(tm, 32));
            const float mn = fmaxf(m_run, tm);
            const float al = __expf(m_run - mn);
            float ps = 0.f;
#pragma unroll
            for (int i = 0; i < 16; ++i) {
                sa[0][i] = __expf(sa[0][i] - mn); ps += sa[0][i];
                sa[1][i] = __expf(sa[1][i] - mn); ps += sa[1][i];
            }
            ps += __shfl_xor(ps, 32);
            l_run = l_run * al + ps;
            m_run = mn;
            O[0] *= al; O[1] *= al; O[2] *= al;

            // ---- PV: O^T += V^T * P^T ----
            const int vtoff = cb ? VT1_OFF : VT0_OFF;
#pragma unroll
            for (int kk = 0; kk < 4; ++kk) {
                const int mf = kk >> 1, base = (kk & 1) * 8;
                const uint32_t A0 = cvtpk(sa[mf][base+0], sa[mf][base+1]);
                const uint32_t A1 = cvtpk(sa[mf][base+2], sa[mf][base+3]);
                const uint32_t B0 = cvtpk(sa[mf][base+4], sa[mf][base+5]);
                const uint32_t B1 = cvtpk(sa[mf][base+6], sa[mf][base+7]);
                const uint32_t rA0 = __shfl_xor(A0, 32);
                const uint32_t rA1 = __shfl_xor(A1, 32);
                const uint32_t rB0 = __shfl_xor(B0, 32);
                const uint32_t rB1 = __shfl_xor(B1, 32);
                F8 pb;
                pb.u[0] = s ? rB0 : A0;
                pb.u[1] = s ? rB1 : A1;
                pb.u[2] = s ? B0  : rA0;
                pb.u[3] = s ? B1  : rA1;
#pragma unroll
                for (int mf2 = 0; mf2 < 3; ++mf2) {
                    const short8 av = *(const short8*)(lds + vtoff + (mf2 * 32 + l31) * 144 + kk * 32 + s * 16);
                    O[mf2] = MFMA32(av, pb.s, O[mf2]);
                }
            }

            if (vt < 3) {
                __syncthreads();         // PV(vt) done; VT[nb] free; XT[nb] staged
                if (wv < 6) vproj(lds, nb ? XT1_OFF : XT0_OFF, nb ? VT1_OFF : VT0_OFF,
                                  wf, B2, mfv, nfv, l31, s);
                if (vt < 2) stage<3>(Xk + eb + (size_t)(vt + 2) * 64 * 96,
                                     lds + (cb ? XT1_OFF : XT0_OFF), t);
                __syncthreads();         // VT[nb] visible; XT(vt+2) staged
            }
        }

        // ---- epilogue: out = x_res + (O/l) * mix ----
        const float inv = 1.f / l_run;
        const size_t rowbase = eb + (size_t)(wv * 32 + l31) * 96;
        float* oo = out + (dir ? TOTEL : 0);
#pragma unroll
        for (int mf = 0; mf < 3; ++mf) {
#pragma unroll
            for (int blk = 0; blk < 4; ++blk) {
                const int d = mf * 32 + blk * 8 + s * 4;
                const float4 mx = *(const float4*)(mixv + d);
                const float4 xr = *(const float4*)(Xq + rowbase + d);
                float4 ov;
                ov.x = fmaf(O[mf][blk*4+0] * inv, mx.x, xr.x);
                ov.y = fmaf(O[mf][blk*4+1] * inv, mx.y, xr.y);
                ov.z = fmaf(O[mf][blk*4+2] * inv, mx.z, xr.z);
                ov.w = fmaf(O[mf][blk*4+3] * inv, mx.w, xr.w);
                *(float4*)(oo + rowbase + d) = ov;
            }
        }
    }
}

extern "C" void kernel_launch(void* const* d_in, const int* in_sizes, int n_in,
                              void* d_out, int out_size, void* d_ws, size_t ws_size,
                              hipStream_t stream) {
    const float* feat_l  = (const float*)d_in[0];
    const float* feat_r  = (const float*)d_in[1];
    const float* g_nl    = (const float*)d_in[2];
    const float* b_nl    = (const float*)d_in[3];
    const float* g_nr    = (const float*)d_in[4];
    const float* b_nr    = (const float*)d_in[5];
    const float* w_l1    = (const float*)d_in[6];
    const float* bias_l1 = (const float*)d_in[7];
    const float* w_r1    = (const float*)d_in[8];
    const float* bias_r1 = (const float*)d_in[9];
    const float* w_l2    = (const float*)d_in[10];
    const float* bias_l2 = (const float*)d_in[11];
    const float* w_r2    = (const float*)d_in[12];
    const float* bias_r2 = (const float*)d_in[13];
    const float* beta    = (const float*)d_in[14];
    const float* gamma   = (const float*)d_in[15];
    float* out = (float*)d_out;

    hipLaunchKernelGGL(scam_fused, dim3(1024), dim3(512), LDS_SZ, stream,
                       feat_l, feat_r, g_nl, b_nl, g_nr, b_nr,
                       w_l1, bias_l1, w_r1, bias_r1, w_l2, bias_l2, w_r2, bias_r2,
                       beta, gamma, out);
}